// Round 15
// baseline (240.822 us; speedup 1.0000x reference)
//
#include <hip/hip_runtime.h>
#include <type_traits>

#define BATCH 2
#define S_LEN 2048
#define DIM 2048
#define NH 16
#define NKV 4
#define HD 128

typedef _Float16 f16x8 __attribute__((ext_vector_type(8)));
typedef float f32x4 __attribute__((ext_vector_type(4)));
typedef unsigned int u32x4 __attribute__((ext_vector_type(4)));
typedef unsigned short u16x4 __attribute__((ext_vector_type(4)));
typedef unsigned short u16x8 __attribute__((ext_vector_type(8)));

__device__ __forceinline__ unsigned short f2h_bits(float f) {
  _Float16 h = (_Float16)f;
  return __builtin_bit_cast(unsigned short, h);
}
__device__ __forceinline__ float h2f(unsigned short u) {
  return (float)__builtin_bit_cast(_Float16, u);
}
__device__ __forceinline__ f16x8 ld8(const unsigned short* p) {
  u32x4 v = *reinterpret_cast<const u32x4*>(p);
  return __builtin_bit_cast(f16x8, v);
}
__device__ __forceinline__ void gload_lds16(const unsigned short* g, unsigned short* l) {
  __builtin_amdgcn_global_load_lds(
      (const __attribute__((address_space(1))) unsigned int*)g,
      (__attribute__((address_space(3))) unsigned int*)l, 16, 0, 0);
}

#define VMWAIT(n) asm volatile("s_waitcnt vmcnt(" #n ")" ::: "memory")

// ---- fused fp32 -> fp16 convert (all 5 tensors) + RoPE tables in tail blocks ----
__global__ __launch_bounds__(256) void cvt_all(const float* __restrict__ x,
                                               const float* __restrict__ Wq,
                                               const float* __restrict__ Wk,
                                               const float* __restrict__ Wv,
                                               const float* __restrict__ Wp,
                                               unsigned short* __restrict__ xb,
                                               unsigned short* __restrict__ wqkv,
                                               unsigned short* __restrict__ wpj,
                                               float* __restrict__ ctab,
                                               float* __restrict__ stab) {
  if (blockIdx.x >= 18432) {  // rope tables: 32768 entries in 128 blocks
    int idx = (blockIdx.x - 18432) * 256 + threadIdx.x;
    int i = idx & 15, t = idx >> 4;
    float inv = exp2f(-(float)i * (13.287712379549449f / 16.0f));
    float f = (float)t * inv;
    ctab[idx] = cosf(f);
    stab[idx] = sinf(f);
    return;
  }
  int i = blockIdx.x * 256 + threadIdx.x;
  const float* src;
  unsigned short* dst;
  if (i < 2097152) {
    src = x + (long)i * 4; dst = xb + (long)i * 4;
  } else if (i < 3145728) {
    int k = i - 2097152; src = Wq + (long)k * 4; dst = wqkv + (long)k * 4;
  } else if (i < 3407872) {
    int k = i - 3145728; src = Wk + (long)k * 4; dst = wqkv + 4194304 + (long)k * 4;
  } else if (i < 3670016) {
    int k = i - 3407872; src = Wv + (long)k * 4; dst = wqkv + 5242880 + (long)k * 4;
  } else {
    int k = i - 3670016; src = Wp + (long)k * 4; dst = wpj + (long)k * 4;
  }
  f32x4 v = *reinterpret_cast<const f32x4*>(src);
  u16x4 o;
  o.x = f2h_bits(v.x); o.y = f2h_bits(v.y); o.z = f2h_bits(v.z); o.w = f2h_bits(v.w);
  *reinterpret_cast<u16x4*>(dst) = o;
}

// ======== GEMM: BK=32, 4 LDS slots, stage-2-ahead, counted vmcnt (round-11 proven) ========
template <int NREP, typename OUT>
__global__ __launch_bounds__(512, 2) void gemm_pl(const unsigned short* __restrict__ A,
                                                  const unsigned short* __restrict__ B,
                                                  OUT* __restrict__ C, int K, int ldc) {
  constexpr int BN = 64 * NREP;
  constexpr int BSH = BN * 32;
  constexpr int TS = 8192 + BSH;
  __shared__ unsigned short lds[4][TS];
  const int tid = threadIdx.x, lane = tid & 63;
  const int wm = tid >> 8, wn = (tid >> 6) & 3;
  const int rlo = lane & 15, hi = lane >> 4;
  const int m0 = blockIdx.x * 256, n0 = blockIdx.y * BN;
  const int NT = K >> 5;
  const int brow = wn * (16 * NREP);

  auto aRow = [&](int sig) { return (sig & 63) + ((sig >> 6) & 1) * 128 + (sig >> 7) * 64; };

  const int sigA0 = tid >> 2, sigA1 = 128 + (tid >> 2);
  const unsigned short* pA0 =
      A + (long)(m0 + aRow(sigA0)) * K + (((tid & 3) ^ ((sigA0 >> 1) & 3)) * 8);
  const unsigned short* pA1 =
      A + (long)(m0 + aRow(sigA1)) * K + (((tid & 3) ^ ((sigA1 >> 1) & 3)) * 8);
  const int rB0 = tid >> 2;
  const unsigned short* pB0 = B + (long)(n0 + rB0) * K + (((tid & 3) ^ ((rB0 >> 1) & 3)) * 8);
  const int idx1 = 512 + (tid & 255);
  const int rB1 = idx1 >> 2;
  const unsigned short* pB1 = B + (long)(n0 + rB1) * K + (((idx1 & 3) ^ ((rB1 >> 1) & 3)) * 8);

  auto stage = [&](int slot) {
    gload_lds16(pA0, &lds[slot][tid * 8]);
    gload_lds16(pA1, &lds[slot][4096 + tid * 8]);
    gload_lds16(pB0, &lds[slot][8192 + tid * 8]);
    if constexpr (NREP == 3) gload_lds16(pB1, &lds[slot][8192 + idx1 * 8]);
    pA0 += 32; pA1 += 32; pB0 += 32;
    if constexpr (NREP == 3) pB1 += 32;
  };

  f32x4 acc[8][NREP] = {};

  auto rdA = [&](const unsigned short* As, int mh, f16x8* af) {
#pragma unroll
    for (int i = 0; i < 4; ++i) {
      int ms = mh * 4 + i;
      int sig = (ms & 3) * 16 + rlo + wm * 64 + (ms >> 2) * 128;
      af[i] = ld8(&As[sig * 32 + ((hi ^ ((sig >> 1) & 3)) * 8)]);
    }
  };
  auto rdB = [&](const unsigned short* Bs, f16x8* bf) {
#pragma unroll
    for (int j = 0; j < NREP; ++j) {
      int r = brow + j * 16 + rlo;
      bf[j] = ld8(&Bs[r * 32 + ((hi ^ ((r >> 1) & 3)) * 8)]);
    }
  };
  auto mm = [&](const f16x8* af, const f16x8* bf, int mh) {
    __builtin_amdgcn_s_setprio(1);
#pragma unroll
    for (int i = 0; i < 4; ++i)
#pragma unroll
      for (int j = 0; j < NREP; ++j)
        acc[mh * 4 + i][j] =
            __builtin_amdgcn_mfma_f32_16x16x32_f16(af[i], bf[j], acc[mh * 4 + i][j], 0, 0, 0);
    __builtin_amdgcn_s_setprio(0);
  };

  stage(0);
  stage(1);
  for (int t = 0; t < NT; ++t) {
    const int slot = t & 3;
    if (t == NT - 1) {
      VMWAIT(0);
    } else {
      if constexpr (NREP == 3) VMWAIT(4); else VMWAIT(3);
    }
    __builtin_amdgcn_s_barrier();
    asm volatile("" ::: "memory");
    if (t + 2 < NT) stage((t + 2) & 3);
    const unsigned short* As = &lds[slot][0];
    const unsigned short* Bs = &lds[slot][8192];
    f16x8 bf[NREP], af0[4], af1[4];
    rdB(Bs, bf);
    rdA(As, 0, af0);
    rdA(As, 1, af1);
    mm(af0, bf, 0);
    mm(af1, bf, 1);
  }

#pragma unroll
  for (int ms = 0; ms < 8; ++ms)
#pragma unroll
    for (int j = 0; j < NREP; ++j) {
      int row = m0 + wm * 128 + ms * 16 + hi * 4;
      int col = n0 + brow + j * 16 + rlo;
#pragma unroll
      for (int r = 0; r < 4; ++r) {
        float v = acc[ms][j][r];
        if constexpr (std::is_same<OUT, float>::value)
          C[(long)(row + r) * ldc + col] = v;
        else
          C[(long)(row + r) * ldc + col] = f2h_bits(v);
      }
    }
}

// ---- RMSNorm + RoPE + gain (vectorized: 16 thr/head-row, u16x8 loads) ----
__global__ __launch_bounds__(256) void qknorm_rope(const unsigned short* __restrict__ qkv,
                                                   const float* __restrict__ ctab,
                                                   const float* __restrict__ stab,
                                                   const float* __restrict__ qgain,
                                                   unsigned short* __restrict__ Qb,
                                                   unsigned short* __restrict__ Kb) {
  const int t = threadIdx.x;
  const int hr = blockIdx.x * 16 + (t >> 4);
  const int j = t & 15;
  const unsigned short* src;
  unsigned short* dst;
  int m, hh;
  bool isQ;
  if (hr < 65536) {
    m = hr >> 4; hh = hr & 15;
    src = qkv + (long)m * 3072 + hh * HD;
    int b = m >> 11, s = m & (S_LEN - 1);
    dst = Qb + (((long)(b * NH + hh)) * S_LEN + s) * HD;
    isQ = true;
  } else {
    int rk = hr - 65536;
    m = rk >> 2; hh = rk & 3;
    src = qkv + (long)m * 3072 + 2048 + hh * HD;
    int b = m >> 11, s = m & (S_LEN - 1);
    dst = Kb + (((long)(b * NKV + hh)) * S_LEN + s) * HD;
    isQ = false;
  }
  const int s = m & (S_LEN - 1);
  u16x8 v = *reinterpret_cast<const u16x8*>(src + j * 8);
  float n[8];
  float ss = 0.f;
#pragma unroll
  for (int e = 0; e < 8; ++e) { n[e] = h2f(v[e]); ss += n[e] * n[e]; }
  ss += __shfl_xor(ss, 1); ss += __shfl_xor(ss, 2);
  ss += __shfl_xor(ss, 4); ss += __shfl_xor(ss, 8);
  float rn = rsqrtf(ss * (1.0f / 128.0f) + 1.1920929e-07f);
#pragma unroll
  for (int e = 0; e < 8; ++e) n[e] *= rn;
  float partner[8];
#pragma unroll
  for (int e = 0; e < 8; ++e) partner[e] = __shfl_xor(n[e], 2);
  if (j < 4) {
    const float* cp = ctab + s * 16 + (j & 1) * 8;
    const float* sp = stab + s * 16 + (j & 1) * 8;
    f32x4 c0 = *reinterpret_cast<const f32x4*>(cp);
    f32x4 c1 = *reinterpret_cast<const f32x4*>(cp + 4);
    f32x4 s0 = *reinterpret_cast<const f32x4*>(sp);
    f32x4 s1 = *reinterpret_cast<const f32x4*>(sp + 4);
    float cs[8] = {c0.x, c0.y, c0.z, c0.w, c1.x, c1.y, c1.z, c1.w};
    float sn[8] = {s0.x, s0.y, s0.z, s0.w, s1.x, s1.y, s1.z, s1.w};
    if (j < 2) {
#pragma unroll
      for (int e = 0; e < 8; ++e) n[e] = n[e] * cs[e] + partner[e] * sn[e];
    } else {
#pragma unroll
      for (int e = 0; e < 8; ++e) n[e] = n[e] * cs[e] - partner[e] * sn[e];
    }
  }
  if (isQ) {
    float g = qgain[hh];
#pragma unroll
    for (int e = 0; e < 8; ++e) n[e] *= g;
  }
  u16x8 o;
#pragma unroll
  for (int e = 0; e < 8; ++e) o[e] = f2h_bits(n[e]);
  *reinterpret_cast<u16x8*>(dst + j * 8) = o;
}

// ---- V transpose via LDS (coalesced both sides) ----
__global__ __launch_bounds__(256) void vtrans(const unsigned short* __restrict__ qkv,
                                              unsigned short* __restrict__ Vt) {
  __shared__ unsigned short tile[128 * 72];
  const int t = threadIdx.x;
  const int g = blockIdx.x;
  const int st = g & 31, kvh = (g >> 5) & 3, b = g >> 7;
  const int s0 = st * 64;
  const unsigned short* base = qkv + ((long)(b * S_LEN + s0)) * 3072 + 2560 + kvh * HD;
#pragma unroll
  for (int k = 0; k < 4; ++k) {
    int idx = t + k * 256;
    int ch = idx & 15;
    int row = idx >> 4;
    u16x8 v = *reinterpret_cast<const u16x8*>(base + (long)row * 3072 + ch * 8);
#pragma unroll
    for (int e = 0; e < 8; ++e) {
      int d = ch * 8 + e;
      tile[d * 72 + (row ^ (((d >> 3) & 7) * 8))] = v[e];
    }
  }
  __syncthreads();
  unsigned short* dstb = Vt + (((long)(b * NKV + kvh)) * HD) * S_LEN + s0;
#pragma unroll
  for (int k = 0; k < 2; ++k) {
    int idx = t + k * 256;
    int d = idx >> 2;
    int sc = (idx & 3) * 16;
    int X = ((d >> 3) & 7) * 8;
    u16x8 a = *reinterpret_cast<const u16x8*>(&tile[d * 72 + (sc ^ X)]);
    u16x8 c2 = *reinterpret_cast<const u16x8*>(&tile[d * 72 + ((sc + 8) ^ X)]);
    *reinterpret_cast<u16x8*>(dstb + (long)d * S_LEN + sc) = a;
    *reinterpret_cast<u16x8*>(dstb + (long)d * S_LEN + sc + 8) = c2;
  }
}

// ======== causal GQA attention (r11 structure; 5 blocks/CU via launch_bounds) ========
#define ATT_C3 ((float)(0.08838834764831845 * (2.0 / 30.0) * 1.4426950408889634))
#define ATT_C4 ((float)(30.0 * 1.4426950408889634))
#define ATT_C5 ((float)(60.0 * 1.4426950408889634))
#define ATT_THR ((float)(8.0 * 1.4426950408889634))

__global__ __launch_bounds__(256, 5) void attn(const unsigned short* __restrict__ Qb,
                                               const unsigned short* __restrict__ Kb,
                                               const unsigned short* __restrict__ Vt,
                                               unsigned short* __restrict__ Yb) {
  __shared__ unsigned short sm[2][8192];
  const int tid = threadIdx.x, wid = tid >> 6, lane = tid & 63;
  const int gx = blockIdx.x;
  const int qq = gx >> 8;
  const int a = (gx >> 5) & 7;
  const int h = gx & 15, b = (gx >> 4) & 1;
  int qb;
  if (qq == 0) qb = 31 - a;
  else if (qq == 1) qb = 16 + a;
  else if (qq == 2) qb = 15 - a;
  else qb = a;

  const int kvh = h >> 2;
  const int rlo = lane & 15, hi = lane >> 4;
  const int q0 = qb * 64 + wid * 16;
  const unsigned short* Kp = Kb + ((long)(b * NKV + kvh)) * S_LEN * HD;
  const unsigned short* Vp = Vt + ((long)(b * NKV + kvh)) * HD * S_LEN;
  const unsigned short* Qp = Qb + (((long)(b * NH + h)) * S_LEN + q0) * HD;
  f16x8 bq[4];
#pragma unroll
  for (int dk = 0; dk < 4; ++dk) bq[dk] = ld8(Qp + rlo * HD + dk * 32 + hi * 8);

  const int kx = rlo & 7;
  const int vx = hi ^ ((rlo >> 1) & 3);
  const unsigned short* aK[4];
#pragma unroll
  for (int dk = 0; dk < 4; ++dk) aK[dk] = &sm[0][rlo * 128 + ((dk * 4 + hi) ^ kx) * 8];
  const unsigned short* aV = &sm[0][4096 + rlo * 32 + vx * 8];

  const int i0 = tid, i1 = tid + 256;
  const int rho0 = i0 >> 4, rho1 = i1 >> 4;
  auto kvperm = [](int r) { return 8 * ((r >> 2) & 3) + (r & 3) + 4 * (r >> 4); };
  const unsigned short* sK0 = Kp + (long)kvperm(rho0) * HD + ((i0 & 15) ^ (rho0 & 7)) * 8;
  const unsigned short* sK1 = Kp + (long)kvperm(rho1) * HD + ((i1 & 15) ^ (rho1 & 7)) * 8;
  const int vd0 = i0 >> 2, vd1 = i1 >> 2;
  const unsigned short* sV0 = Vp + (long)vd0 * S_LEN + ((i0 & 3) ^ ((vd0 >> 1) & 3)) * 8;
  const unsigned short* sV1 = Vp + (long)vd1 * S_LEN + ((i1 & 3) ^ ((vd1 >> 1) & 3)) * 8;
  unsigned short* dK0 = &sm[0][rho0 * 128 + (i0 & 15) * 8];
  unsigned short* dK1 = &sm[0][rho1 * 128 + (i1 & 15) * 8];
  unsigned short* dV0 = &sm[0][4096 + vd0 * 32 + (i0 & 3) * 8];
  unsigned short* dV1 = &sm[0][4096 + vd1 * 32 + (i1 & 3) * 8];

  f32x4 acc[8] = {};
  float m2c = ATT_C4 + 128.0f;
  float l_run = 0.0f;
  const int nt = 2 * qb + 2;
  const int twlast = 2 * qb + (wid >> 1);

#define STAGE(SLOT)                                                       \
  {                                                                       \
    gload_lds16(sK0, dK0 + (SLOT)*8192);                                  \
    gload_lds16(sK1, dK1 + (SLOT)*8192);                                  \
    gload_lds16(sV0, dV0 + (SLOT)*8192);                                  \
    gload_lds16(sV1, dV1 + (SLOT)*8192);                                  \
    sK0 += 4096; sK1 += 4096; sV0 += 32; sV1 += 32;                       \
  }

#define COMPUTE(T, SLOT)                                                              \
  {                                                                                   \
    f16x8 ka0[4], ka1[4];                                                             \
    _Pragma("unroll")                                                                 \
    for (int dk = 0; dk < 4; ++dk) {                                                  \
      ka0[dk] = ld8(aK[dk] + (SLOT)*8192);                                            \
      ka1[dk] = ld8(aK[dk] + (SLOT)*8192 + 2048);                                     \
    }                                                                                 \
    f32x4 s0 = {0.f, 0.f, 0.f, 0.f}, s1 = s0;                                         \
    __builtin_amdgcn_s_setprio(1);                                                    \
    _Pragma("unroll")                                                                 \
    for (int dk = 0; dk < 4; ++dk) {                                                  \
      s0 = __builtin_amdgcn_mfma_f32_16x16x32_f16(ka0[dk], bq[dk], s0, 0, 0, 0);      \
      s1 = __builtin_amdgcn_mfma_f32_16x16x32_f16(ka1[dk], bq[dk], s1, 0, 0, 0);      \
    }                                                                                 \
    __builtin_amdgcn_s_setprio(0);                                                    \
    float ea[8];                                                                      \
    _Pragma("unroll")                                                                 \
    for (int jj = 0; jj < 8; ++jj) {                                                  \
      float sc = (jj < 4) ? s0[jj] : s1[jj - 4];                                      \
      float u = __builtin_amdgcn_exp2f(sc * ATT_C3);                                  \
      float rr = __builtin_amdgcn_rcpf(u + 1.0f);                                     \
      ea[jj] = fmaf(-ATT_C5, rr, m2c);                                                \
    }                                                                                 \
    if ((T) == twlast) {                                                              \
      int qrel = q0 + rlo - 32 * (T);                                                 \
      _Pragma("unroll")                                                               \
      for (int jj = 0; jj < 8; ++jj)                                                  \
        ea[jj] = (8 * hi + jj > qrel) ? -1e30f : ea[jj];                              \
    }                                                                                 \
    float pm = ea[0];                                                                 \
    _Pragma("unroll")                                                                 \
    for (int jj = 1; jj < 8; ++jj) pm = fmaxf(pm, ea[jj]);                            \
    if (!__all(pm <= ATT_THR)) {                                                      \
      float red = fmaxf(pm, __shfl_xor(pm, 16));                                      \
      red = fmaxf(red, __shfl_xor(red, 32));                                          \
      red = fmaxf(red, 0.0f);                                                         \
      m2c -= red;                                                                     \
      float ff = __builtin_amdgcn_exp2f(-red);                                        \
      l_run *= ff;                                                                    \
      _Pragma("unroll")                                                               \
      for (int dt = 0; dt < 8; ++dt) acc[dt] *= ff;                                   \
      _Pragma("unroll")                                                               \
      for (int jj = 0; jj < 8; ++jj) ea[jj] -= red;                                   \
    }                                                                                 \
    float pv[8];                                                                      \
    _Pragma("unroll")                                                                 \
    for (int jj = 0; jj < 8; ++jj) pv[jj] = __builtin_amdgcn_exp2f(ea[jj]);           \
    l_run += ((pv[0] + pv[1]) + (pv[2] + pv[3])) + ((pv[4] + pv[5]) + (pv[6] + pv[7]));\
    u32x4 pk;                                                                         \
    pk.x = __builtin_bit_cast(unsigned int, __builtin_amdgcn_cvt_pkrtz(pv[0], pv[1]));\
    pk.y = __builtin_bit_cast(unsigned int, __builtin_amdgcn_cvt_pkrtz(pv[2], pv[3]));\
    pk.z = __builtin_bit_cast(unsigned int, __builtin_amdgcn_cvt_pkrtz(pv[4], pv[5]));\
    pk.w = __builtin_bit_cast(unsigned int, __builtin_amdgcn_cvt_pkrtz(pv[6], pv[7]));\
    f16x8 bp = __builtin_bit_cast(f16x8, pk);                                         \
    __builtin_amdgcn_s_setprio(1);                                                    \
    _Pragma("unroll")                                                                 \
    for (int g = 0; g < 2; ++g) {                                                     \
      f16x8 av[4];                                                                    \
      _Pragma("unroll")                                                               \
      for (int i = 0; i < 4; ++i) av[i] = ld8(aV + (SLOT)*8192 + (g * 4 + i) * 512);  \
      _Pragma("unroll")                                                               \
      for (int i = 0; i < 4; ++i)                                                     \
        acc[g * 4 + i] =                                                              \
            __builtin_amdgcn_mfma_f32_16x16x32_f16(av[i], bp, acc[g * 4 + i], 0, 0, 0);\
    }                                                                                 \
    __builtin_amdgcn_s_setprio(0);                                                    \
  }

  STAGE(0);
  for (int t = 0; t < nt; t += 2) {
    VMWAIT(0);
    __builtin_amdgcn_s_barrier();
    asm volatile("" ::: "memory");
    STAGE(1);
    if (t <= twlast) COMPUTE(t, 0);
    VMWAIT(0);
    __builtin_amdgcn_s_barrier();
    asm volatile("" ::: "memory");
    if (t + 2 < nt) STAGE(0);
    if (t + 1 <= twlast) COMPUTE(t + 1, 1);
  }
#undef STAGE
#undef COMPUTE

  float l = l_run + __shfl_xor(l_run, 16);
  l += __shfl_xor(l, 32);
  float inv = 1.0f / l;
  unsigned short* yp = Yb + ((long)(b * S_LEN + q0 + rlo)) * DIM + h * HD + 4 * hi;
#pragma unroll
  for (int dt = 0; dt < 8; ++dt) {
    u16x4 o;
#pragma unroll
    for (int r = 0; r < 4; ++r) o[r] = f2h_bits(acc[dt][r] * inv);
    *reinterpret_cast<u16x4*>(yp + dt * 16) = o;
  }
}

extern "C" void kernel_launch(void* const* d_in, const int* in_sizes, int n_in,
                              void* d_out, int out_size, void* d_ws, size_t ws_size,
                              hipStream_t stream) {
  const float* x = (const float*)d_in[0];
  const float* Wq = (const float*)d_in[1];
  const float* Wk = (const float*)d_in[2];
  const float* Wv = (const float*)d_in[3];
  const float* Wp = (const float*)d_in[4];
  const float* qg = (const float*)d_in[5];
  float* out = (float*)d_out;

  char* ws = (char*)d_ws;
  size_t off = 0;
  auto alloc = [&](size_t bytes) {
    char* p = ws + off;
    off += (bytes + 255) & ~(size_t)255;
    return p;
  };
  unsigned short* xb   = (unsigned short*)alloc(8388608ull * 2);
  unsigned short* wqkv = (unsigned short*)alloc(6291456ull * 2);
  unsigned short* wpj  = (unsigned short*)alloc(4194304ull * 2);
  unsigned short* qkv  = (unsigned short*)alloc(4096ull * 3072 * 2);
  unsigned short* Qbuf = (unsigned short*)alloc(8388608ull * 2);
  unsigned short* Kb   = (unsigned short*)alloc(2097152ull * 2);
  unsigned short* Vt   = (unsigned short*)alloc(2097152ull * 2);
  unsigned short* Yb   = (unsigned short*)alloc(8388608ull * 2);
  float* ctab = (float*)alloc(32768ull * 4);
  float* stab = (float*)alloc(32768ull * 4);

  cvt_all<<<18560, 256, 0, stream>>>(x, Wq, Wk, Wv, Wp, xb, wqkv, wpj, ctab, stab);

  // qkv = x @ [Wq;Wk;Wv]^T : M=4096 N=3072 K=2048  (256x192 tiles -> 256 blocks)
  gemm_pl<3, unsigned short><<<dim3(16, 16), 512, 0, stream>>>(xb, wqkv, qkv, 2048, 3072);

  qknorm_rope<<<5120, 256, 0, stream>>>(qkv, ctab, stab, qg, Qbuf, Kb);
  vtrans<<<256, 256, 0, stream>>>(qkv, Vt);

  attn<<<1024, 256, 0, stream>>>(Qbuf, Kb, Vt, Yb);

  // out = y @ Wproj^T : M=4096 N=2048 K=2048  (256x128 tiles -> 256 blocks)
  gemm_pl<2, float><<<dim3(16, 16), 512, 0, stream>>>(Yb, wpj, out, 2048, 2048);
}

// Round 16
// 186.490 us; speedup vs baseline: 1.2913x; 1.2913x over previous
//
#include <hip/hip_runtime.h>
#include <type_traits>

#define BATCH 2
#define S_LEN 2048
#define DIM 2048
#define NH 16
#define NKV 4
#define HD 128

typedef _Float16 f16x8 __attribute__((ext_vector_type(8)));
typedef float f32x4 __attribute__((ext_vector_type(4)));
typedef unsigned int u32x4 __attribute__((ext_vector_type(4)));
typedef unsigned short u16x4 __attribute__((ext_vector_type(4)));
typedef unsigned short u16x8 __attribute__((ext_vector_type(8)));

__device__ __forceinline__ unsigned short f2h_bits(float f) {
  _Float16 h = (_Float16)f;
  return __builtin_bit_cast(unsigned short, h);
}
__device__ __forceinline__ float h2f(unsigned short u) {
  return (float)__builtin_bit_cast(_Float16, u);
}
__device__ __forceinline__ f16x8 ld8(const unsigned short* p) {
  u32x4 v = *reinterpret_cast<const u32x4*>(p);
  return __builtin_bit_cast(f16x8, v);
}
__device__ __forceinline__ void gload_lds16(const unsigned short* g, unsigned short* l) {
  __builtin_amdgcn_global_load_lds(
      (const __attribute__((address_space(1))) unsigned int*)g,
      (__attribute__((address_space(3))) unsigned int*)l, 16, 0, 0);
}

#define VMWAIT(n) asm volatile("s_waitcnt vmcnt(" #n ")" ::: "memory")

// ---- fused fp32 -> fp16 convert (all 5 tensors) + RoPE tables in tail blocks ----
__global__ __launch_bounds__(256) void cvt_all(const float* __restrict__ x,
                                               const float* __restrict__ Wq,
                                               const float* __restrict__ Wk,
                                               const float* __restrict__ Wv,
                                               const float* __restrict__ Wp,
                                               unsigned short* __restrict__ xb,
                                               unsigned short* __restrict__ wqkv,
                                               unsigned short* __restrict__ wpj,
                                               float* __restrict__ ctab,
                                               float* __restrict__ stab) {
  if (blockIdx.x >= 18432) {  // rope tables: 32768 entries in 128 blocks
    int idx = (blockIdx.x - 18432) * 256 + threadIdx.x;
    int i = idx & 15, t = idx >> 4;
    float inv = exp2f(-(float)i * (13.287712379549449f / 16.0f));
    float f = (float)t * inv;
    ctab[idx] = cosf(f);
    stab[idx] = sinf(f);
    return;
  }
  int i = blockIdx.x * 256 + threadIdx.x;
  const float* src;
  unsigned short* dst;
  if (i < 2097152) {
    src = x + (long)i * 4; dst = xb + (long)i * 4;
  } else if (i < 3145728) {
    int k = i - 2097152; src = Wq + (long)k * 4; dst = wqkv + (long)k * 4;
  } else if (i < 3407872) {
    int k = i - 3145728; src = Wk + (long)k * 4; dst = wqkv + 4194304 + (long)k * 4;
  } else if (i < 3670016) {
    int k = i - 3407872; src = Wv + (long)k * 4; dst = wqkv + 5242880 + (long)k * 4;
  } else {
    int k = i - 3670016; src = Wp + (long)k * 4; dst = wpj + (long)k * 4;
  }
  f32x4 v = *reinterpret_cast<const f32x4*>(src);
  u16x4 o;
  o.x = f2h_bits(v.x); o.y = f2h_bits(v.y); o.z = f2h_bits(v.z); o.w = f2h_bits(v.w);
  *reinterpret_cast<u16x4*>(dst) = o;
}

// ======== GEMM: BK=32, 4 LDS slots, stage-2-ahead, counted vmcnt (round-11 proven) ========
template <int NREP, typename OUT>
__global__ __launch_bounds__(512, 2) void gemm_pl(const unsigned short* __restrict__ A,
                                                  const unsigned short* __restrict__ B,
                                                  OUT* __restrict__ C, int K, int ldc) {
  constexpr int BN = 64 * NREP;
  constexpr int BSH = BN * 32;
  constexpr int TS = 8192 + BSH;
  __shared__ unsigned short lds[4][TS];
  const int tid = threadIdx.x, lane = tid & 63;
  const int wm = tid >> 8, wn = (tid >> 6) & 3;
  const int rlo = lane & 15, hi = lane >> 4;
  const int m0 = blockIdx.x * 256, n0 = blockIdx.y * BN;
  const int NT = K >> 5;
  const int brow = wn * (16 * NREP);

  auto aRow = [&](int sig) { return (sig & 63) + ((sig >> 6) & 1) * 128 + (sig >> 7) * 64; };

  const int sigA0 = tid >> 2, sigA1 = 128 + (tid >> 2);
  const unsigned short* pA0 =
      A + (long)(m0 + aRow(sigA0)) * K + (((tid & 3) ^ ((sigA0 >> 1) & 3)) * 8);
  const unsigned short* pA1 =
      A + (long)(m0 + aRow(sigA1)) * K + (((tid & 3) ^ ((sigA1 >> 1) & 3)) * 8);
  const int rB0 = tid >> 2;
  const unsigned short* pB0 = B + (long)(n0 + rB0) * K + (((tid & 3) ^ ((rB0 >> 1) & 3)) * 8);
  const int idx1 = 512 + (tid & 255);
  const int rB1 = idx1 >> 2;
  const unsigned short* pB1 = B + (long)(n0 + rB1) * K + (((idx1 & 3) ^ ((rB1 >> 1) & 3)) * 8);

  auto stage = [&](int slot) {
    gload_lds16(pA0, &lds[slot][tid * 8]);
    gload_lds16(pA1, &lds[slot][4096 + tid * 8]);
    gload_lds16(pB0, &lds[slot][8192 + tid * 8]);
    if constexpr (NREP == 3) gload_lds16(pB1, &lds[slot][8192 + idx1 * 8]);
    pA0 += 32; pA1 += 32; pB0 += 32;
    if constexpr (NREP == 3) pB1 += 32;
  };

  f32x4 acc[8][NREP] = {};

  auto rdA = [&](const unsigned short* As, int mh, f16x8* af) {
#pragma unroll
    for (int i = 0; i < 4; ++i) {
      int ms = mh * 4 + i;
      int sig = (ms & 3) * 16 + rlo + wm * 64 + (ms >> 2) * 128;
      af[i] = ld8(&As[sig * 32 + ((hi ^ ((sig >> 1) & 3)) * 8)]);
    }
  };
  auto rdB = [&](const unsigned short* Bs, f16x8* bf) {
#pragma unroll
    for (int j = 0; j < NREP; ++j) {
      int r = brow + j * 16 + rlo;
      bf[j] = ld8(&Bs[r * 32 + ((hi ^ ((r >> 1) & 3)) * 8)]);
    }
  };
  auto mm = [&](const f16x8* af, const f16x8* bf, int mh) {
    __builtin_amdgcn_s_setprio(1);
#pragma unroll
    for (int i = 0; i < 4; ++i)
#pragma unroll
      for (int j = 0; j < NREP; ++j)
        acc[mh * 4 + i][j] =
            __builtin_amdgcn_mfma_f32_16x16x32_f16(af[i], bf[j], acc[mh * 4 + i][j], 0, 0, 0);
    __builtin_amdgcn_s_setprio(0);
  };

  stage(0);
  stage(1);
  for (int t = 0; t < NT; ++t) {
    const int slot = t & 3;
    if (t == NT - 1) {
      VMWAIT(0);
    } else {
      if constexpr (NREP == 3) VMWAIT(4); else VMWAIT(3);
    }
    __builtin_amdgcn_s_barrier();
    asm volatile("" ::: "memory");
    if (t + 2 < NT) stage((t + 2) & 3);
    const unsigned short* As = &lds[slot][0];
    const unsigned short* Bs = &lds[slot][8192];
    f16x8 bf[NREP], af0[4], af1[4];
    rdB(Bs, bf);
    rdA(As, 0, af0);
    rdA(As, 1, af1);
    mm(af0, bf, 0);
    mm(af1, bf, 1);
  }

#pragma unroll
  for (int ms = 0; ms < 8; ++ms)
#pragma unroll
    for (int j = 0; j < NREP; ++j) {
      int row = m0 + wm * 128 + ms * 16 + hi * 4;
      int col = n0 + brow + j * 16 + rlo;
#pragma unroll
      for (int r = 0; r < 4; ++r) {
        float v = acc[ms][j][r];
        if constexpr (std::is_same<OUT, float>::value)
          C[(long)(row + r) * ldc + col] = v;
        else
          C[(long)(row + r) * ldc + col] = f2h_bits(v);
      }
    }
}

// ---- RMSNorm + RoPE + gain (vectorized: 16 thr/head-row, u16x8 loads) ----
__global__ __launch_bounds__(256) void qknorm_rope(const unsigned short* __restrict__ qkv,
                                                   const float* __restrict__ ctab,
                                                   const float* __restrict__ stab,
                                                   const float* __restrict__ qgain,
                                                   unsigned short* __restrict__ Qb,
                                                   unsigned short* __restrict__ Kb) {
  const int t = threadIdx.x;
  const int hr = blockIdx.x * 16 + (t >> 4);
  const int j = t & 15;
  const unsigned short* src;
  unsigned short* dst;
  int m, hh;
  bool isQ;
  if (hr < 65536) {
    m = hr >> 4; hh = hr & 15;
    src = qkv + (long)m * 3072 + hh * HD;
    int b = m >> 11, s = m & (S_LEN - 1);
    dst = Qb + (((long)(b * NH + hh)) * S_LEN + s) * HD;
    isQ = true;
  } else {
    int rk = hr - 65536;
    m = rk >> 2; hh = rk & 3;
    src = qkv + (long)m * 3072 + 2048 + hh * HD;
    int b = m >> 11, s = m & (S_LEN - 1);
    dst = Kb + (((long)(b * NKV + hh)) * S_LEN + s) * HD;
    isQ = false;
  }
  const int s = m & (S_LEN - 1);
  u16x8 v = *reinterpret_cast<const u16x8*>(src + j * 8);
  float n[8];
  float ss = 0.f;
#pragma unroll
  for (int e = 0; e < 8; ++e) { n[e] = h2f(v[e]); ss += n[e] * n[e]; }
  ss += __shfl_xor(ss, 1); ss += __shfl_xor(ss, 2);
  ss += __shfl_xor(ss, 4); ss += __shfl_xor(ss, 8);
  float rn = rsqrtf(ss * (1.0f / 128.0f) + 1.1920929e-07f);
#pragma unroll
  for (int e = 0; e < 8; ++e) n[e] *= rn;
  float partner[8];
#pragma unroll
  for (int e = 0; e < 8; ++e) partner[e] = __shfl_xor(n[e], 2);
  if (j < 4) {
    const float* cp = ctab + s * 16 + (j & 1) * 8;
    const float* sp = stab + s * 16 + (j & 1) * 8;
    f32x4 c0 = *reinterpret_cast<const f32x4*>(cp);
    f32x4 c1 = *reinterpret_cast<const f32x4*>(cp + 4);
    f32x4 s0 = *reinterpret_cast<const f32x4*>(sp);
    f32x4 s1 = *reinterpret_cast<const f32x4*>(sp + 4);
    float cs[8] = {c0.x, c0.y, c0.z, c0.w, c1.x, c1.y, c1.z, c1.w};
    float sn[8] = {s0.x, s0.y, s0.z, s0.w, s1.x, s1.y, s1.z, s1.w};
    if (j < 2) {
#pragma unroll
      for (int e = 0; e < 8; ++e) n[e] = n[e] * cs[e] + partner[e] * sn[e];
    } else {
#pragma unroll
      for (int e = 0; e < 8; ++e) n[e] = n[e] * cs[e] - partner[e] * sn[e];
    }
  }
  if (isQ) {
    float g = qgain[hh];
#pragma unroll
    for (int e = 0; e < 8; ++e) n[e] *= g;
  }
  u16x8 o;
#pragma unroll
  for (int e = 0; e < 8; ++e) o[e] = f2h_bits(n[e]);
  *reinterpret_cast<u16x8*>(dst + j * 8) = o;
}

// ---- V transpose via LDS (coalesced both sides) ----
__global__ __launch_bounds__(256) void vtrans(const unsigned short* __restrict__ qkv,
                                              unsigned short* __restrict__ Vt) {
  __shared__ unsigned short tile[128 * 72];
  const int t = threadIdx.x;
  const int g = blockIdx.x;
  const int st = g & 31, kvh = (g >> 5) & 3, b = g >> 7;
  const int s0 = st * 64;
  const unsigned short* base = qkv + ((long)(b * S_LEN + s0)) * 3072 + 2560 + kvh * HD;
#pragma unroll
  for (int k = 0; k < 4; ++k) {
    int idx = t + k * 256;
    int ch = idx & 15;
    int row = idx >> 4;
    u16x8 v = *reinterpret_cast<const u16x8*>(base + (long)row * 3072 + ch * 8);
#pragma unroll
    for (int e = 0; e < 8; ++e) {
      int d = ch * 8 + e;
      tile[d * 72 + (row ^ (((d >> 3) & 7) * 8))] = v[e];
    }
  }
  __syncthreads();
  unsigned short* dstb = Vt + (((long)(b * NKV + kvh)) * HD) * S_LEN + s0;
#pragma unroll
  for (int k = 0; k < 2; ++k) {
    int idx = t + k * 256;
    int d = idx >> 2;
    int sc = (idx & 3) * 16;
    int X = ((d >> 3) & 7) * 8;
    u16x8 a = *reinterpret_cast<const u16x8*>(&tile[d * 72 + (sc ^ X)]);
    u16x8 c2 = *reinterpret_cast<const u16x8*>(&tile[d * 72 + ((sc + 8) ^ X)]);
    *reinterpret_cast<u16x8*>(dstb + (long)d * S_LEN + sc) = a;
    *reinterpret_cast<u16x8*>(dstb + (long)d * S_LEN + sc + 8) = c2;
  }
}

// ======== causal GQA attention (r13 exact: heavy-first quarters, invariant addressing) ========
#define ATT_C3 ((float)(0.08838834764831845 * (2.0 / 30.0) * 1.4426950408889634))
#define ATT_C4 ((float)(30.0 * 1.4426950408889634))
#define ATT_C5 ((float)(60.0 * 1.4426950408889634))
#define ATT_THR ((float)(8.0 * 1.4426950408889634))

__global__ __launch_bounds__(256, 4) void attn(const unsigned short* __restrict__ Qb,
                                               const unsigned short* __restrict__ Kb,
                                               const unsigned short* __restrict__ Vt,
                                               unsigned short* __restrict__ Yb) {
  __shared__ unsigned short sm[2][8192];
  const int tid = threadIdx.x, wid = tid >> 6, lane = tid & 63;
  const int gx = blockIdx.x;
  const int qq = gx >> 8;
  const int a = (gx >> 5) & 7;
  const int h = gx & 15, b = (gx >> 4) & 1;
  int qb;
  if (qq == 0) qb = 31 - a;
  else if (qq == 1) qb = 16 + a;
  else if (qq == 2) qb = 15 - a;
  else qb = a;

  const int kvh = h >> 2;
  const int rlo = lane & 15, hi = lane >> 4;
  const int q0 = qb * 64 + wid * 16;
  const unsigned short* Kp = Kb + ((long)(b * NKV + kvh)) * S_LEN * HD;
  const unsigned short* Vp = Vt + ((long)(b * NKV + kvh)) * HD * S_LEN;
  const unsigned short* Qp = Qb + (((long)(b * NH + h)) * S_LEN + q0) * HD;
  f16x8 bq[4];
#pragma unroll
  for (int dk = 0; dk < 4; ++dk) bq[dk] = ld8(Qp + rlo * HD + dk * 32 + hi * 8);

  const int kx = rlo & 7;
  const int vx = hi ^ ((rlo >> 1) & 3);
  const unsigned short* aK[4];
#pragma unroll
  for (int dk = 0; dk < 4; ++dk) aK[dk] = &sm[0][rlo * 128 + ((dk * 4 + hi) ^ kx) * 8];
  const unsigned short* aV = &sm[0][4096 + rlo * 32 + vx * 8];

  const int i0 = tid, i1 = tid + 256;
  const int rho0 = i0 >> 4, rho1 = i1 >> 4;
  auto kvperm = [](int r) { return 8 * ((r >> 2) & 3) + (r & 3) + 4 * (r >> 4); };
  const unsigned short* sK0 = Kp + (long)kvperm(rho0) * HD + ((i0 & 15) ^ (rho0 & 7)) * 8;
  const unsigned short* sK1 = Kp + (long)kvperm(rho1) * HD + ((i1 & 15) ^ (rho1 & 7)) * 8;
  const int vd0 = i0 >> 2, vd1 = i1 >> 2;
  const unsigned short* sV0 = Vp + (long)vd0 * S_LEN + ((i0 & 3) ^ ((vd0 >> 1) & 3)) * 8;
  const unsigned short* sV1 = Vp + (long)vd1 * S_LEN + ((i1 & 3) ^ ((vd1 >> 1) & 3)) * 8;
  unsigned short* dK0 = &sm[0][rho0 * 128 + (i0 & 15) * 8];
  unsigned short* dK1 = &sm[0][rho1 * 128 + (i1 & 15) * 8];
  unsigned short* dV0 = &sm[0][4096 + vd0 * 32 + (i0 & 3) * 8];
  unsigned short* dV1 = &sm[0][4096 + vd1 * 32 + (i1 & 3) * 8];

  f32x4 acc[8] = {};
  float m2c = ATT_C4 + 128.0f;
  float l_run = 0.0f;
  const int nt = 2 * qb + 2;
  const int twlast = 2 * qb + (wid >> 1);

#define STAGE(SLOT)                                                       \
  {                                                                       \
    gload_lds16(sK0, dK0 + (SLOT)*8192);                                  \
    gload_lds16(sK1, dK1 + (SLOT)*8192);                                  \
    gload_lds16(sV0, dV0 + (SLOT)*8192);                                  \
    gload_lds16(sV1, dV1 + (SLOT)*8192);                                  \
    sK0 += 4096; sK1 += 4096; sV0 += 32; sV1 += 32;                       \
  }

#define COMPUTE(T, SLOT)                                                              \
  {                                                                                   \
    f16x8 ka0[4], ka1[4];                                                             \
    _Pragma("unroll")                                                                 \
    for (int dk = 0; dk < 4; ++dk) {                                                  \
      ka0[dk] = ld8(aK[dk] + (SLOT)*8192);                                            \
      ka1[dk] = ld8(aK[dk] + (SLOT)*8192 + 2048);                                     \
    }                                                                                 \
    f32x4 s0 = {0.f, 0.f, 0.f, 0.f}, s1 = s0;                                         \
    __builtin_amdgcn_s_setprio(1);                                                    \
    _Pragma("unroll")                                                                 \
    for (int dk = 0; dk < 4; ++dk) {                                                  \
      s0 = __builtin_amdgcn_mfma_f32_16x16x32_f16(ka0[dk], bq[dk], s0, 0, 0, 0);      \
      s1 = __builtin_amdgcn_mfma_f32_16x16x32_f16(ka1[dk], bq[dk], s1, 0, 0, 0);      \
    }                                                                                 \
    __builtin_amdgcn_s_setprio(0);                                                    \
    float ea[8];                                                                      \
    _Pragma("unroll")                                                                 \
    for (int jj = 0; jj < 8; ++jj) {                                                  \
      float sc = (jj < 4) ? s0[jj] : s1[jj - 4];                                      \
      float u = __builtin_amdgcn_exp2f(sc * ATT_C3);                                  \
      float rr = __builtin_amdgcn_rcpf(u + 1.0f);                                     \
      ea[jj] = fmaf(-ATT_C5, rr, m2c);                                                \
    }                                                                                 \
    if ((T) == twlast) {                                                              \
      int qrel = q0 + rlo - 32 * (T);                                                 \
      _Pragma("unroll")                                                               \
      for (int jj = 0; jj < 8; ++jj)                                                  \
        ea[jj] = (8 * hi + jj > qrel) ? -1e30f : ea[jj];                              \
    }                                                                                 \
    float pm = ea[0];                                                                 \
    _Pragma("unroll")                                                                 \
    for (int jj = 1; jj < 8; ++jj) pm = fmaxf(pm, ea[jj]);                            \
    if (!__all(pm <= ATT_THR)) {                                                      \
      float red = fmaxf(pm, __shfl_xor(pm, 16));                                      \
      red = fmaxf(red, __shfl_xor(red, 32));                                          \
      red = fmaxf(red, 0.0f);                                                         \
      m2c -= red;                                                                     \
      float ff = __builtin_amdgcn_exp2f(-red);                                        \
      l_run *= ff;                                                                    \
      _Pragma("unroll")                                                               \
      for (int dt = 0; dt < 8; ++dt) acc[dt] *= ff;                                   \
      _Pragma("unroll")                                                               \
      for (int jj = 0; jj < 8; ++jj) ea[jj] -= red;                                   \
    }                                                                                 \
    float pv[8];                                                                      \
    _Pragma("unroll")                                                                 \
    for (int jj = 0; jj < 8; ++jj) pv[jj] = __builtin_amdgcn_exp2f(ea[jj]);           \
    l_run += ((pv[0] + pv[1]) + (pv[2] + pv[3])) + ((pv[4] + pv[5]) + (pv[6] + pv[7]));\
    u32x4 pk;                                                                         \
    pk.x = __builtin_bit_cast(unsigned int, __builtin_amdgcn_cvt_pkrtz(pv[0], pv[1]));\
    pk.y = __builtin_bit_cast(unsigned int, __builtin_amdgcn_cvt_pkrtz(pv[2], pv[3]));\
    pk.z = __builtin_bit_cast(unsigned int, __builtin_amdgcn_cvt_pkrtz(pv[4], pv[5]));\
    pk.w = __builtin_bit_cast(unsigned int, __builtin_amdgcn_cvt_pkrtz(pv[6], pv[7]));\
    f16x8 bp = __builtin_bit_cast(f16x8, pk);                                         \
    __builtin_amdgcn_s_setprio(1);                                                    \
    _Pragma("unroll")                                                                 \
    for (int g = 0; g < 2; ++g) {                                                     \
      f16x8 av[4];                                                                    \
      _Pragma("unroll")                                                               \
      for (int i = 0; i < 4; ++i) av[i] = ld8(aV + (SLOT)*8192 + (g * 4 + i) * 512);  \
      _Pragma("unroll")                                                               \
      for (int i = 0; i < 4; ++i)                                                     \
        acc[g * 4 + i] =                                                              \
            __builtin_amdgcn_mfma_f32_16x16x32_f16(av[i], bp, acc[g * 4 + i], 0, 0, 0);\
    }                                                                                 \
    __builtin_amdgcn_s_setprio(0);                                                    \
  }

  STAGE(0);
  for (int t = 0; t < nt; t += 2) {
    VMWAIT(0);
    __builtin_amdgcn_s_barrier();
    asm volatile("" ::: "memory");
    STAGE(1);
    if (t <= twlast) COMPUTE(t, 0);
    VMWAIT(0);
    __builtin_amdgcn_s_barrier();
    asm volatile("" ::: "memory");
    if (t + 2 < nt) STAGE(0);
    if (t + 1 <= twlast) COMPUTE(t + 1, 1);
  }
#undef STAGE
#undef COMPUTE

  float l = l_run + __shfl_xor(l_run, 16);
  l += __shfl_xor(l, 32);
  float inv = 1.0f / l;
  unsigned short* yp = Yb + ((long)(b * S_LEN + q0 + rlo)) * DIM + h * HD + 4 * hi;
#pragma unroll
  for (int dt = 0; dt < 8; ++dt) {
    u16x4 o;
#pragma unroll
    for (int r = 0; r < 4; ++r) o[r] = f2h_bits(acc[dt][r] * inv);
    *reinterpret_cast<u16x4*>(yp + dt * 16) = o;
  }
}

extern "C" void kernel_launch(void* const* d_in, const int* in_sizes, int n_in,
                              void* d_out, int out_size, void* d_ws, size_t ws_size,
                              hipStream_t stream) {
  const float* x = (const float*)d_in[0];
  const float* Wq = (const float*)d_in[1];
  const float* Wk = (const float*)d_in[2];
  const float* Wv = (const float*)d_in[3];
  const float* Wp = (const float*)d_in[4];
  const float* qg = (const float*)d_in[5];
  float* out = (float*)d_out;

  char* ws = (char*)d_ws;
  size_t off = 0;
  auto alloc = [&](size_t bytes) {
    char* p = ws + off;
    off += (bytes + 255) & ~(size_t)255;
    return p;
  };
  unsigned short* xb   = (unsigned short*)alloc(8388608ull * 2);
  unsigned short* wqkv = (unsigned short*)alloc(6291456ull * 2);
  unsigned short* wpj  = (unsigned short*)alloc(4194304ull * 2);
  unsigned short* qkv  = (unsigned short*)alloc(4096ull * 3072 * 2);
  unsigned short* Qbuf = (unsigned short*)alloc(8388608ull * 2);
  unsigned short* Kb   = (unsigned short*)alloc(2097152ull * 2);
  unsigned short* Vt   = (unsigned short*)alloc(2097152ull * 2);
  unsigned short* Yb   = (unsigned short*)alloc(8388608ull * 2);
  float* ctab = (float*)alloc(32768ull * 4);
  float* stab = (float*)alloc(32768ull * 4);

  cvt_all<<<18560, 256, 0, stream>>>(x, Wq, Wk, Wv, Wp, xb, wqkv, wpj, ctab, stab);

  // qkv = x @ [Wq;Wk;Wv]^T : M=4096 N=3072 K=2048  (256x192 tiles -> 256 blocks)
  gemm_pl<3, unsigned short><<<dim3(16, 16), 512, 0, stream>>>(xb, wqkv, qkv, 2048, 3072);

  qknorm_rope<<<5120, 256, 0, stream>>>(qkv, ctab, stab, qg, Qbuf, Kb);
  vtrans<<<256, 256, 0, stream>>>(qkv, Vt);

  attn<<<1024, 256, 0, stream>>>(Qbuf, Kb, Vt, Yb);

  // out = y @ Wproj^T : M=4096 N=2048 K=2048  (256x128 tiles -> 256 blocks)
  gemm_pl<2, float><<<dim3(16, 16), 512, 0, stream>>>(Yb, wpj, out, 2048, 2048);
}